// Round 11
// baseline (273.043 us; speedup 1.0000x reference)
//
#include <hip/hip_runtime.h>
#include <hip/hip_fp16.h>

#define BATCH 256
#define ICAPS 1152
#define OCAPS 10
#define OD    160
#define BLOCK 768            // 12 waves, 1 block/CU (LDS-bound), 256 blocks = 256 CUs
#define NW    12
#define NPAIR 384            // pair P owns rows P, P+384 (registers), 768+P (LDS)

// x held on-chip as NAMED uint4 SSA values (R9/R10's xr[2][40] alloca was never
// promoted by the backend -> scratch spill, FETCH 490MB/WRITE 304MB at VGPR=84).
// 20 named uint4 = 80 VGPRs of fp16 x per lane; no alloca, must be registers.

#define LOADQ(dst, p) do {                                                  \
    const float4 fa_ = *(const float4*)(p);                                 \
    const float4 fb_ = *(const float4*)((p) + 4);                           \
    __half2 h0_ = __floats2half2_rn(fa_.x, fa_.y);                          \
    __half2 h1_ = __floats2half2_rn(fa_.z, fa_.w);                          \
    __half2 h2_ = __floats2half2_rn(fb_.x, fb_.y);                          \
    __half2 h3_ = __floats2half2_rn(fb_.z, fb_.w);                          \
    dst.x = *(unsigned*)&h0_; dst.y = *(unsigned*)&h1_;                     \
    dst.z = *(unsigned*)&h2_; dst.w = *(unsigned*)&h3_;                     \
} while (0)

#define DOT8(q, wp, accum) do {                                             \
    float2 f_;                                                              \
    f_ = __half22float2(*(const __half2*)&(q).x); accum += f_.x*(wp)[0] + f_.y*(wp)[1]; \
    f_ = __half22float2(*(const __half2*)&(q).y); accum += f_.x*(wp)[2] + f_.y*(wp)[3]; \
    f_ = __half22float2(*(const __half2*)&(q).z); accum += f_.x*(wp)[4] + f_.y*(wp)[5]; \
    f_ = __half22float2(*(const __half2*)&(q).w); accum += f_.x*(wp)[6] + f_.y*(wp)[7]; \
} while (0)

#define ACC8(q, cc, ap) do {                                                \
    float2 f_;                                                              \
    f_ = __half22float2(*(const __half2*)&(q).x); (ap)[0]+=(cc)*f_.x; (ap)[1]+=(cc)*f_.y; \
    f_ = __half22float2(*(const __half2*)&(q).y); (ap)[2]+=(cc)*f_.x; (ap)[3]+=(cc)*f_.y; \
    f_ = __half22float2(*(const __half2*)&(q).z); (ap)[4]+=(cc)*f_.x; (ap)[5]+=(cc)*f_.y; \
    f_ = __half22float2(*(const __half2*)&(q).w); (ap)[6]+=(cc)*f_.x; (ap)[7]+=(cc)*f_.y; \
} while (0)

#define DOT_OL(OL) do {                                                     \
    const int og_ = half * 5 + OL;                                          \
    float wv_[16];                                                          \
    *(float4*)&wv_[0]  = *(const float4*)&v_lds[og_*16+0];                  \
    *(float4*)&wv_[4]  = *(const float4*)&v_lds[og_*16+4];                  \
    *(float4*)&wv_[8]  = *(const float4*)&v_lds[og_*16+8];                  \
    *(float4*)&wv_[12] = *(const float4*)&v_lds[og_*16+12];                 \
    float dA_ = 0.f, dB_ = 0.f, dL_ = 0.f;                                  \
    DOT8(A##OL##a, wv_,   dA_); DOT8(A##OL##b, wv_+8, dA_);                 \
    DOT8(B##OL##a, wv_,   dB_); DOT8(B##OL##b, wv_+8, dB_);                 \
    const uint4 u0_ = xl4[(half*10 + OL*2    ) * NPAIR + P];                \
    const uint4 u1_ = xl4[(half*10 + OL*2 + 1) * NPAIR + P];                \
    DOT8(u0_, wv_, dL_); DOT8(u1_, wv_+8, dL_);                             \
    bA[OL] += dA_; bB[OL] += dB_; bL[OL] += dL_;                            \
} while (0)

#define SOFTMAX5(bv, cv) do {                                               \
    float ot_[5];                                                           \
    _Pragma("unroll") for (int j_ = 0; j_ < 5; ++j_) ot_[j_] = __shfl_xor(bv[j_], 1, 64); \
    float m_ = bv[0];                                                       \
    _Pragma("unroll") for (int j_ = 0; j_ < 5; ++j_) { m_ = fmaxf(m_, bv[j_]); m_ = fmaxf(m_, ot_[j_]); } \
    float s_ = 0.f, e_[5];                                                  \
    _Pragma("unroll") for (int j_ = 0; j_ < 5; ++j_) { e_[j_] = __expf(bv[j_] - m_); s_ += e_[j_] + __expf(ot_[j_] - m_); } \
    const float inv_ = 1.f / s_;                                            \
    _Pragma("unroll") for (int j_ = 0; j_ < 5; ++j_) cv[j_] = e_[j_] * inv_; \
} while (0)

#define SUM_OL(OL) do {                                                     \
    float ac_[16];                                                          \
    _Pragma("unroll") for (int k_ = 0; k_ < 16; ++k_) ac_[k_] = 0.f;        \
    ACC8(A##OL##a, cA[OL], ac_); ACC8(A##OL##b, cA[OL], ac_+8);             \
    ACC8(B##OL##a, cB[OL], ac_); ACC8(B##OL##b, cB[OL], ac_+8);             \
    const uint4 u0_ = xl4[(half*10 + OL*2    ) * NPAIR + P];                \
    const uint4 u1_ = xl4[(half*10 + OL*2 + 1) * NPAIR + P];                \
    ACC8(u0_, cL[OL], ac_); ACC8(u1_, cL[OL], ac_+8);                       \
    _Pragma("unroll") for (int mm_ = 2; mm_ <= 8; mm_ <<= 1)                \
        _Pragma("unroll") for (int k_ = 0; k_ < 16; ++k_) ac_[k_] += __shfl_xor(ac_[k_], mm_, 64); \
    if ((ln & 14) == 0) {                                                   \
        float* pp_ = &part[w][ln >> 4][half * 80 + OL * 16];                \
        _Pragma("unroll") for (int k_ = 0; k_ < 16; ++k_) pp_[k_] = ac_[k_]; \
    }                                                                       \
} while (0)

__global__ __launch_bounds__(BLOCK, 3) void k_caps(const float* __restrict__ x,
                                                   float* __restrict__ out) {
    __shared__ uint4 xl4[20 * NPAIR];           // 122880 B: rows 768..1151
    __shared__ float part[NW][4][OD];           // 30720 B partial col-sums
    __shared__ __align__(16) float v_lds[OD];

    const int b    = blockIdx.x;
    const int t    = threadIdx.x;
    const int w    = t >> 6;
    const int ln   = t & 63;
    const int half = ln & 1;                    // 0: d 0..79 (o 0..4), 1: d 80..159 (o 5..9)
    const int P    = t >> 1;                    // pair id 0..383

    const float* xp = x + (size_t)b * (ICAPS * OD);

    uint4 A0a,A0b,A1a,A1b,A2a,A2b,A3a,A3b,A4a,A4b;   // row P      (80 halves)
    uint4 B0a,B0b,B1a,B1b,B2a,B2b,B3a,B3b,B4a,B4b;   // row P+384  (80 halves)
    float bA[5] = {0,0,0,0,0}, bB[5] = {0,0,0,0,0}, bL[5] = {0,0,0,0,0};
    float cA[5], cB[5], cL[5];
    #pragma unroll
    for (int j = 0; j < 5; ++j) { cA[j] = 1.f; cB[j] = 1.f; cL[j] = 1.f; }

    // ---------- load pass: fp32 -> fp16 into regs + LDS (only HBM read) ----------
    {
        const float* bpA = xp + (size_t)P * OD + half * 80;
        LOADQ(A0a, bpA +  0); LOADQ(A0b, bpA +  8);
        LOADQ(A1a, bpA + 16); LOADQ(A1b, bpA + 24);
        LOADQ(A2a, bpA + 32); LOADQ(A2b, bpA + 40);
        LOADQ(A3a, bpA + 48); LOADQ(A3b, bpA + 56);
        LOADQ(A4a, bpA + 64); LOADQ(A4b, bpA + 72);
        const float* bpB = xp + (size_t)(P + NPAIR) * OD + half * 80;
        LOADQ(B0a, bpB +  0); LOADQ(B0b, bpB +  8);
        LOADQ(B1a, bpB + 16); LOADQ(B1b, bpB + 24);
        LOADQ(B2a, bpB + 32); LOADQ(B2b, bpB + 40);
        LOADQ(B3a, bpB + 48); LOADQ(B3b, bpB + 56);
        LOADQ(B4a, bpB + 64); LOADQ(B4b, bpB + 72);
        const float* bpL = xp + (size_t)(768 + P) * OD + half * 80;
        #pragma unroll
        for (int j = 0; j < 10; ++j) {
            uint4 u;
            LOADQ(u, bpL + j * 8);
            xl4[(half * 10 + j) * NPAIR + P] = u;   // lane-contiguous ds_write_b128
        }
    }
    __syncthreads();

    for (int it = 0; it <= 3; ++it) {
        if (it > 0) {
            DOT_OL(0); DOT_OL(1); DOT_OL(2); DOT_OL(3); DOT_OL(4);
            SOFTMAX5(bA, cA);
            SOFTMAX5(bB, cB);
            SOFTMAX5(bL, cL);
        }
        SUM_OL(0); SUM_OL(1); SUM_OL(2); SUM_OL(3); SUM_OL(4);
        __syncthreads();
        if (t < OD) {   // reduce 48 partials + squash
            float s = 0.f;
            #pragma unroll
            for (int ww = 0; ww < NW; ++ww)
                #pragma unroll
                for (int g = 0; g < 4; ++g) s += part[ww][g][t];
            if (it == 0) s *= 0.1f;
            float sq = s * s;
            #pragma unroll
            for (int mm = 1; mm < 16; mm <<= 1) sq += __shfl_xor(sq, mm, 64);
            const float sc = sqrtf(sq) / (1.f + sq);
            if (it == 3) out[(size_t)b * OD + t] = s * sc;
            else         v_lds[t] = s * sc;
        }
        __syncthreads();
    }
}

extern "C" void kernel_launch(void* const* d_in, const int* in_sizes, int n_in,
                              void* d_out, int out_size, void* d_ws, size_t ws_size,
                              hipStream_t stream) {
    const float* x = (const float*)d_in[0];
    float* vout = (float*)d_out;
    k_caps<<<BATCH, BLOCK, 0, stream>>>(x, vout);
}

// Round 12
// 271.187 us; speedup vs baseline: 1.0068x; 1.0068x over previous
//
#include <hip/hip_runtime.h>
#include <hip/hip_fp16.h>

#define BATCH 256
#define ICAPS 1152
#define OCAPS 10
#define OD    160
#define BLOCK 768            // 12 waves, 1 block/CU, 256 blocks = 256 CUs
#define NW    12
#define NPAIR 384            // pair P owns rows P, P+384 (registers), 768+P (LDS)

// x on-chip: 20 named uint4 (80 VGPRs fp16 x) per lane + 384 rows in LDS.
// R9-R11 all compiled to VGPR=84 (= 512/6: backend budgeting 6 waves/EU) and
// spilled the tile to scratch regardless of __launch_bounds__(,3). Direct
// backend attribute amdgpu_waves_per_eu(3,3) sets the true budget (~168).

#define LOADQ(dst, p) do {                                                  \
    const float4 fa_ = *(const float4*)(p);                                 \
    const float4 fb_ = *(const float4*)((p) + 4);                           \
    __half2 h0_ = __floats2half2_rn(fa_.x, fa_.y);                          \
    __half2 h1_ = __floats2half2_rn(fa_.z, fa_.w);                          \
    __half2 h2_ = __floats2half2_rn(fb_.x, fb_.y);                          \
    __half2 h3_ = __floats2half2_rn(fb_.z, fb_.w);                          \
    dst.x = *(unsigned*)&h0_; dst.y = *(unsigned*)&h1_;                     \
    dst.z = *(unsigned*)&h2_; dst.w = *(unsigned*)&h3_;                     \
} while (0)

#define DOT8(q, wp, accum) do {                                             \
    float2 f_;                                                              \
    f_ = __half22float2(*(const __half2*)&(q).x); accum += f_.x*(wp)[0] + f_.y*(wp)[1]; \
    f_ = __half22float2(*(const __half2*)&(q).y); accum += f_.x*(wp)[2] + f_.y*(wp)[3]; \
    f_ = __half22float2(*(const __half2*)&(q).z); accum += f_.x*(wp)[4] + f_.y*(wp)[5]; \
    f_ = __half22float2(*(const __half2*)&(q).w); accum += f_.x*(wp)[6] + f_.y*(wp)[7]; \
} while (0)

#define ACC8(q, cc, ap) do {                                                \
    float2 f_;                                                              \
    f_ = __half22float2(*(const __half2*)&(q).x); (ap)[0]+=(cc)*f_.x; (ap)[1]+=(cc)*f_.y; \
    f_ = __half22float2(*(const __half2*)&(q).y); (ap)[2]+=(cc)*f_.x; (ap)[3]+=(cc)*f_.y; \
    f_ = __half22float2(*(const __half2*)&(q).z); (ap)[4]+=(cc)*f_.x; (ap)[5]+=(cc)*f_.y; \
    f_ = __half22float2(*(const __half2*)&(q).w); (ap)[6]+=(cc)*f_.x; (ap)[7]+=(cc)*f_.y; \
} while (0)

#define DOT_OL(OL) do {                                                     \
    const int og_ = half * 5 + OL;                                          \
    float wv_[16];                                                          \
    *(float4*)&wv_[0]  = *(const float4*)&v_lds[og_*16+0];                  \
    *(float4*)&wv_[4]  = *(const float4*)&v_lds[og_*16+4];                  \
    *(float4*)&wv_[8]  = *(const float4*)&v_lds[og_*16+8];                  \
    *(float4*)&wv_[12] = *(const float4*)&v_lds[og_*16+12];                 \
    float dA_ = 0.f, dB_ = 0.f, dL_ = 0.f;                                  \
    DOT8(A##OL##a, wv_,   dA_); DOT8(A##OL##b, wv_+8, dA_);                 \
    DOT8(B##OL##a, wv_,   dB_); DOT8(B##OL##b, wv_+8, dB_);                 \
    const uint4 u0_ = xl4[(half*10 + OL*2    ) * NPAIR + P];                \
    const uint4 u1_ = xl4[(half*10 + OL*2 + 1) * NPAIR + P];                \
    DOT8(u0_, wv_, dL_); DOT8(u1_, wv_+8, dL_);                             \
    bA[OL] += dA_; bB[OL] += dB_; bL[OL] += dL_;                            \
} while (0)

#define SOFTMAX5(bv, cv) do {                                               \
    float ot_[5];                                                           \
    _Pragma("unroll") for (int j_ = 0; j_ < 5; ++j_) ot_[j_] = __shfl_xor(bv[j_], 1, 64); \
    float m_ = bv[0];                                                       \
    _Pragma("unroll") for (int j_ = 0; j_ < 5; ++j_) { m_ = fmaxf(m_, bv[j_]); m_ = fmaxf(m_, ot_[j_]); } \
    float s_ = 0.f, e_[5];                                                  \
    _Pragma("unroll") for (int j_ = 0; j_ < 5; ++j_) { e_[j_] = __expf(bv[j_] - m_); s_ += e_[j_] + __expf(ot_[j_] - m_); } \
    const float inv_ = 1.f / s_;                                            \
    _Pragma("unroll") for (int j_ = 0; j_ < 5; ++j_) cv[j_] = e_[j_] * inv_; \
} while (0)

// parity-preserving reduction over strides 2..32: lanes 0 (half=0) and 1
// (half=1) end with the wave's full parity-sums -> part[w][OD]
#define SUM_OL(OL) do {                                                     \
    float ac_[16];                                                          \
    _Pragma("unroll") for (int k_ = 0; k_ < 16; ++k_) ac_[k_] = 0.f;        \
    ACC8(A##OL##a, cA[OL], ac_); ACC8(A##OL##b, cA[OL], ac_+8);             \
    ACC8(B##OL##a, cB[OL], ac_); ACC8(B##OL##b, cB[OL], ac_+8);             \
    const uint4 u0_ = xl4[(half*10 + OL*2    ) * NPAIR + P];                \
    const uint4 u1_ = xl4[(half*10 + OL*2 + 1) * NPAIR + P];                \
    ACC8(u0_, cL[OL], ac_); ACC8(u1_, cL[OL], ac_+8);                       \
    _Pragma("unroll") for (int mm_ = 2; mm_ <= 32; mm_ <<= 1)               \
        _Pragma("unroll") for (int k_ = 0; k_ < 16; ++k_) ac_[k_] += __shfl_xor(ac_[k_], mm_, 64); \
    if (ln < 2) {                                                           \
        float* pp_ = &part[w][half * 80 + OL * 16];                         \
        _Pragma("unroll") for (int k_ = 0; k_ < 16; ++k_) pp_[k_] = ac_[k_]; \
    }                                                                       \
} while (0)

__global__ __attribute__((amdgpu_waves_per_eu(3, 3)))
__launch_bounds__(BLOCK) void k_caps(const float* __restrict__ x,
                                     float* __restrict__ out) {
    __shared__ uint4 xl4[20 * NPAIR];           // 122880 B: rows 768..1151
    __shared__ float part[NW][OD];              // 7680 B per-wave partials
    __shared__ __align__(16) float v_lds[OD];

    const int b    = blockIdx.x;
    const int t    = threadIdx.x;
    const int w    = t >> 6;
    const int ln   = t & 63;
    const int half = ln & 1;                    // 0: d 0..79 (o 0..4), 1: d 80..159
    const int P    = t >> 1;                    // pair id 0..383

    const float* xp = x + (size_t)b * (ICAPS * OD);

    uint4 A0a,A0b,A1a,A1b,A2a,A2b,A3a,A3b,A4a,A4b;   // row P      (80 halves)
    uint4 B0a,B0b,B1a,B1b,B2a,B2b,B3a,B3b,B4a,B4b;   // row P+384  (80 halves)
    float bA[5] = {0,0,0,0,0}, bB[5] = {0,0,0,0,0}, bL[5] = {0,0,0,0,0};
    float cA[5], cB[5], cL[5];
    #pragma unroll
    for (int j = 0; j < 5; ++j) { cA[j] = 1.f; cB[j] = 1.f; cL[j] = 1.f; }

    // ---------- load pass: fp32 -> fp16 into regs + LDS (only HBM read) ----------
    {
        const float* bpA = xp + (size_t)P * OD + half * 80;
        LOADQ(A0a, bpA +  0); LOADQ(A0b, bpA +  8);
        LOADQ(A1a, bpA + 16); LOADQ(A1b, bpA + 24);
        LOADQ(A2a, bpA + 32); LOADQ(A2b, bpA + 40);
        LOADQ(A3a, bpA + 48); LOADQ(A3b, bpA + 56);
        LOADQ(A4a, bpA + 64); LOADQ(A4b, bpA + 72);
        const float* bpB = xp + (size_t)(P + NPAIR) * OD + half * 80;
        LOADQ(B0a, bpB +  0); LOADQ(B0b, bpB +  8);
        LOADQ(B1a, bpB + 16); LOADQ(B1b, bpB + 24);
        LOADQ(B2a, bpB + 32); LOADQ(B2b, bpB + 40);
        LOADQ(B3a, bpB + 48); LOADQ(B3b, bpB + 56);
        LOADQ(B4a, bpB + 64); LOADQ(B4b, bpB + 72);
        const float* bpL = xp + (size_t)(768 + P) * OD + half * 80;
        #pragma unroll
        for (int j = 0; j < 10; ++j) {
            uint4 u;
            LOADQ(u, bpL + j * 8);
            xl4[(half * 10 + j) * NPAIR + P] = u;   // lane-contiguous ds_write_b128
        }
    }
    __syncthreads();

    for (int it = 0; it <= 3; ++it) {
        if (it > 0) {
            DOT_OL(0); DOT_OL(1); DOT_OL(2); DOT_OL(3); DOT_OL(4);
            SOFTMAX5(bA, cA);
            SOFTMAX5(bB, cB);
            SOFTMAX5(bL, cL);
        }
        SUM_OL(0); SUM_OL(1); SUM_OL(2); SUM_OL(3); SUM_OL(4);
        __syncthreads();
        if (t < OD) {   // reduce 12 wave-partials + squash
            float s = 0.f;
            #pragma unroll
            for (int ww = 0; ww < NW; ++ww) s += part[ww][t];
            if (it == 0) s *= 0.1f;
            float sq = s * s;
            #pragma unroll
            for (int mm = 1; mm < 16; mm <<= 1) sq += __shfl_xor(sq, mm, 64);
            const float sc = sqrtf(sq) / (1.f + sq);
            if (it == 3) out[(size_t)b * OD + t] = s * sc;
            else         v_lds[t] = s * sc;
        }
        __syncthreads();
    }
}

extern "C" void kernel_launch(void* const* d_in, const int* in_sizes, int n_in,
                              void* d_out, int out_size, void* d_ws, size_t ws_size,
                              hipStream_t stream) {
    const float* x = (const float*)d_in[0];
    float* vout = (float*)d_out;
    k_caps<<<BATCH, BLOCK, 0, stream>>>(x, vout);
}